// Round 1
// baseline (97142.548 us; speedup 1.0000x reference)
//
#include <hip/hip_runtime.h>
#include <stdint.h>
#include <math.h>

// Problem constants
#define Bv      512
#define INv     64
#define Hv      512
#define OUTv    12
#define Tv      31
#define S0v     8
#define STEPS   (Tv*Bv)        // 15872 sequential LSTM steps per layer
#define EPOCHS_ (STEPS+1)      // +1 pipeline skew for layer 1

// Workgroup roles
#define KA      32             // layer-0 WGs (16 h-indices each)
#define KB      64             // layer-1 WGs (8 h-indices each)
#define KBAR    (KA+KB)        // 96 barrier participants
#define KPP     16             // postproc WGs
#define NBLK    (KBAR+KPP)     // 112 blocks <= 256 CUs -> co-resident
#define FLAG_STRIDE 32         // uint32 stride = 128B per flag line

// ---------------- threefry2x32 (JAX-exact) ----------------
__device__ __forceinline__ uint32_t rotl32(uint32_t v, int r){ return (v<<r)|(v>>(32-r)); }

__device__ __forceinline__ void threefry2x32(uint32_t k0, uint32_t k1,
                                             uint32_t x0, uint32_t x1,
                                             uint32_t& o0, uint32_t& o1) {
  uint32_t ks2 = k0 ^ k1 ^ 0x1BD11BDAu;
  x0 += k0; x1 += k1;
#define TFR(r) { x0 += x1; x1 = rotl32(x1, r); x1 ^= x0; }
  TFR(13) TFR(15) TFR(26) TFR(6)
  x0 += k1;  x1 += ks2 + 1u;
  TFR(17) TFR(29) TFR(16) TFR(24)
  x0 += ks2; x1 += k0 + 2u;
  TFR(13) TFR(15) TFR(26) TFR(6)
  x0 += k0;  x1 += k1 + 3u;
  TFR(17) TFR(29) TFR(16) TFR(24)
  x0 += k1;  x1 += ks2 + 4u;
  TFR(13) TFR(15) TFR(26) TFR(6)
  x0 += ks2; x1 += k0 + 5u;
#undef TFR
  o0 = x0; o1 = x1;
}

// Partitionable-threefry 32-bit draw for flat index j: fold(TF(key,(0,j)))
__device__ __forceinline__ uint32_t tf_bits32(uint32_t k0, uint32_t k1, uint32_t j) {
  uint32_t a, b;
  threefry2x32(k0, k1, 0u, j, a, b);
  return a ^ b;
}

__device__ __forceinline__ float u32_to_uniform(uint32_t bits) {
  // JAX: bitcast(bits>>9 | 0x3F800000) - 1, then *(1-tiny)+tiny, then max(tiny,.)
  float f = __uint_as_float(0x3F800000u | (bits >> 9)) - 1.0f;
  const float TINY = 1.17549435e-38f;
  return fmaxf(TINY, f + TINY);
}

__device__ __forceinline__ float gumbelf(uint32_t bits) {
  float u = u32_to_uniform(bits);
  return -logf(-logf(u));
}

__device__ __forceinline__ float sigmf(float x) {
  if (x >= 0.f) { float z = expf(-x); return 1.f/(1.f+z); }
  float z = expf(x); return z/(1.f+z);
}

// Butterfly: halve per-lane row-partials across lanes (xor mask m).
// After halving stages + final allreduce stages, each lane holds full sums.
template<int N>
__device__ __forceinline__ void bfly_halve(float* v, int m) {
  int lane = threadIdx.x & 63;
  bool up = (lane & m) != 0;
#pragma unroll
  for (int j = 0; j < N/2; ++j) {
    float send = up ? v[j] : v[j + N/2];
    float recv = __shfl_xor(send, m, 64);
    v[j] = (up ? v[j + N/2] : v[j]) + recv;
  }
}

// Poll all KBAR flags >= tgt (valid range guard vs 0xAA poison). Wave 0 only.
__device__ __forceinline__ void poll_all(uint32_t* flags, uint32_t tgt) {
  int lane = threadIdx.x & 63;
  uint32_t* p1 = flags + lane * FLAG_STRIDE;
  uint32_t* p2 = flags + (lane + 64) * FLAG_STRIDE;
  bool has2 = lane < (KBAR - 64);
  for (;;) {
    uint32_t v1 = __hip_atomic_load(p1, __ATOMIC_RELAXED, __HIP_MEMORY_SCOPE_AGENT);
    uint32_t v2 = has2 ? __hip_atomic_load(p2, __ATOMIC_RELAXED, __HIP_MEMORY_SCOPE_AGENT)
                       : tgt;
    bool ok1 = (v1 >= tgt) && (v1 <= (uint32_t)EPOCHS_);
    bool ok2 = (v2 >= tgt) && (v2 <= (uint32_t)EPOCHS_);
    if (__all(ok1 && ok2)) return;
  }
}

__global__ __launch_bounds__(256, 1)
void net_persistent(const float* __restrict__ Wih0, const float* __restrict__ Whh0,
                    const float* __restrict__ b0,
                    const float* __restrict__ Wih1, const float* __restrict__ Whh1,
                    const float* __restrict__ b1,
                    const float* __restrict__ gamma, const float* __restrict__ beta,
                    const float* __restrict__ Wout, const float* __restrict__ bout,
                    const float* __restrict__ h0in, const float* __restrict__ c0in,
                    float* __restrict__ out, uint32_t* __restrict__ wsu)
{
  uint32_t* flags = wsu;                               // 96 * 128B
  float* h0ring = (float*)(wsu + KBAR * FLAG_STRIDE);  // 4 * 512 floats
  float* ys1 = h0ring + 4 * Hv;                        // STEPS * 512 floats (~31MB)

  const int bid = blockIdx.x;
  const int tid = threadIdx.x;
  const int wave = tid >> 6;
  const int lane = tid & 63;

  // static LDS shared by both roles (allocated once per block)
  __shared__ float cbuf_s[64];   // constant gate addend (xw0-const or b1)
  __shared__ float gbuf_s[64];   // reduced gate pre-activations per epoch
  __shared__ float cst_s[16];    // persistent c-state slice
  __shared__ float Wout_s[OUTv*Hv];
  __shared__ float mu_s[Hv], isd_s[Hv], gam_s[Hv], bet_s[Hv];

  if (bid < KBAR) {
    // ---------------- LSTM roles ----------------
    const bool isL0 = (bid < KA);
    const int HS    = isL0 ? 16 : 8;               // h-indices owned
    const int hbase = isL0 ? bid*16 : (bid-KA)*8;

    // Register-resident weight slice: 128 floats/thread.
    // Row mapping: wave q <-> gate q; local row j <-> h-index hbase+j.
    float w[128];
    if (isL0) {
      const float* base = Whh0 + (size_t)(wave*Hv + hbase)*Hv + lane*8;
#pragma unroll
      for (int j = 0; j < 16; ++j)
#pragma unroll
        for (int c = 0; c < 8; ++c)
          w[j*8+c] = base[(size_t)j*Hv + c];
    } else {
      int col0 = lane * 16;                         // 0..1023 over [x | h]
      const float* M = (col0 < 512) ? Wih1 : Whh1;
      int cadj = (col0 < 512) ? col0 : (col0 - 512);
      const float* base = M + (size_t)(wave*Hv + hbase)*Hv + cadj;
#pragma unroll
      for (int j = 0; j < 8; ++j)
#pragma unroll
        for (int c = 0; c < 16; ++c)
          w[j*16+c] = base[(size_t)j*Hv + c];
    }

    // Constant gate addend: layer0 folds x=ones -> sum(Wih0 row)+b0; layer1: b1.
    for (int r = tid; r < 4*HS; r += 256) {
      int q = r / HS, j = r % HS;
      int grow = q*Hv + hbase + j;
      float v;
      if (isL0) {
        float s = b0[grow];
        for (int k = 0; k < INv; ++k) s += Wih0[(size_t)grow*INv + k];
        v = s;
      } else {
        v = b1[grow];
      }
      cbuf_s[r] = v;
    }
    for (int j = tid; j < HS; j += 256)
      cst_s[j] = c0in[(isL0 ? 0 : Hv) + hbase + j];
    __syncthreads();

    for (int e = 0; e < EPOCHS_; ++e) {
      const bool active = isL0 ? (e < STEPS) : (e >= 1);
      if (active) {
        const int s = isL0 ? e : (e - 1);
        if (isL0) {
          const float* hsrc = (s == 0) ? h0in : (h0ring + ((s-1)&3)*Hv);
          const float4* hv = (const float4*)(hsrc + lane*8);
          float4 A = hv[0], Bq = hv[1];
          float vin[8] = {A.x,A.y,A.z,A.w,Bq.x,Bq.y,Bq.z,Bq.w};
          float acc[16];
#pragma unroll
          for (int j = 0; j < 16; ++j) {
            float a = 0.f;
#pragma unroll
            for (int c = 0; c < 8; ++c) a = fmaf(w[j*8+c], vin[c], a);
            acc[j] = a;
          }
          bfly_halve<16>(acc, 32);
          bfly_halve<8>(acc, 16);
          bfly_halve<4>(acc, 8);
          bfly_halve<2>(acc, 4);
          acc[0] += __shfl_xor(acc[0], 2, 64);
          acc[0] += __shfl_xor(acc[0], 1, 64);
          if ((lane & 3) == 0) gbuf_s[wave*16 + (lane>>2)] = acc[0];
        } else {
          const float* xsrc = h0ring + (s&3)*Hv;                       // ys0[s]
          const float* hsrc = (s == 0) ? (h0in + Hv) : (ys1 + (size_t)(s-1)*Hv);
          int col0 = lane * 16;
          const float* src = (col0 < 512) ? (xsrc + col0) : (hsrc + (col0 - 512));
          const float4* sv = (const float4*)src;
          float4 A = sv[0], Bq = sv[1], C = sv[2], D = sv[3];
          float vin[16] = {A.x,A.y,A.z,A.w,Bq.x,Bq.y,Bq.z,Bq.w,
                           C.x,C.y,C.z,C.w,D.x,D.y,D.z,D.w};
          float acc[8];
#pragma unroll
          for (int j = 0; j < 8; ++j) {
            float a = 0.f;
#pragma unroll
            for (int c = 0; c < 16; ++c) a = fmaf(w[j*16+c], vin[c], a);
            acc[j] = a;
          }
          bfly_halve<8>(acc, 32);
          bfly_halve<4>(acc, 16);
          bfly_halve<2>(acc, 8);
          acc[0] += __shfl_xor(acc[0], 4, 64);
          acc[0] += __shfl_xor(acc[0], 2, 64);
          acc[0] += __shfl_xor(acc[0], 1, 64);
          if ((lane & 7) == 0) gbuf_s[wave*8 + (lane>>3)] = acc[0];
        }
      }
      __syncthreads();
      if (active && tid < HS) {
        const int s = isL0 ? e : (e - 1);
        float gi = gbuf_s[0*HS+tid] + cbuf_s[0*HS+tid];
        float gf = gbuf_s[1*HS+tid] + cbuf_s[1*HS+tid];
        float gg = gbuf_s[2*HS+tid] + cbuf_s[2*HS+tid];
        float go = gbuf_s[3*HS+tid] + cbuf_s[3*HS+tid];
        float cc = sigmf(gf)*cst_s[tid] + sigmf(gi)*tanhf(gg);
        float hh = sigmf(go)*tanhf(cc);
        cst_s[tid] = cc;
        if (isL0) h0ring[(s&3)*Hv + hbase + tid] = hh;
        else      ys1[(size_t)s*Hv + hbase + tid] = hh;
      }
      __syncthreads();  // drains vmcnt: all waves' global stores complete
      if (tid == 0) {
        __builtin_amdgcn_fence(__ATOMIC_RELEASE, "agent");
        __hip_atomic_store(flags + bid*FLAG_STRIDE, (uint32_t)(e+1),
                           __ATOMIC_RELAXED, __HIP_MEMORY_SCOPE_AGENT);
      }
      if (tid < 64) poll_all(flags, (uint32_t)(e+1));
      __syncthreads();
      __builtin_amdgcn_fence(__ATOMIC_ACQUIRE, "agent");
    }
  } else {
    // ---------------- Postprocess role (off critical path) ----------------
    const int p = bid - KBAR;
    for (int r = tid; r < OUTv*Hv; r += 256) Wout_s[r] = Wout[r];
    for (int h = tid; h < Hv; h += 256) { gam_s[h] = gamma[h]; bet_s[h] = beta[h]; }
    float bo[OUTv];
#pragma unroll
    for (int o = 0; o < OUTv; ++o) bo[o] = bout[o];
    __syncthreads();

    for (int i = p; i < Tv; i += KPP) {
      const uint32_t tgt = (uint32_t)(Bv*(i+1) + 1);  // layer1 iter-i done epoch
      if (tid < 64) poll_all(flags, tgt);
      __syncthreads();
      __builtin_amdgcn_fence(__ATOMIC_ACQUIRE, "agent");

      const float* Y = ys1 + (size_t)i * Bv * Hv;

      // BatchNorm training-mode stats over B (biased var)
      for (int h = tid; h < Hv; h += 256) {
        double sum = 0.0, sq = 0.0;
        for (int b = 0; b < Bv; ++b) {
          double v = (double)Y[(size_t)b*Hv + h];
          sum += v; sq += v*v;
        }
        double mu = sum * (1.0/512.0);
        double var = sq * (1.0/512.0) - mu*mu;
        if (var < 0.0) var = 0.0;
        mu_s[h]  = (float)mu;
        isd_s[h] = (float)(1.0 / sqrt(var + 1e-5));
      }
      __syncthreads();

      // keys[i] = both outputs of TF(key42, (0, i))   [partitionable split]
      uint32_t k0, k1;
      threefry2x32(0u, 42u, 0u, (uint32_t)i, k0, k1);

      for (int b = tid; b < Bv; b += 256) {
        float lg[OUTv];
#pragma unroll
        for (int o = 0; o < OUTv; ++o) lg[o] = 0.f;
        const float* Yb = Y + (size_t)b * Hv;
        for (int h = 0; h < Hv; ++h) {
          float yn = (Yb[h] - mu_s[h]) * isd_s[h] * gam_s[h] + bet_s[h];
          float gv = expf(-yn*yn);
#pragma unroll
          for (int o = 0; o < OUTv; ++o) lg[o] = fmaf(gv, Wout_s[o*Hv + h], lg[o]);
        }
#pragma unroll
        for (int o = 0; o < OUTv; ++o) lg[o] += bo[o];

        int action; float la;
        if (i < 15) {  // full categorical over 12
          float best = -3.0e38f; int bi = 0; float bl = lg[0];
#pragma unroll
          for (int o = 0; o < OUTv; ++o) {
            uint32_t bits = tf_bits32(k0, k1, (uint32_t)(b*12 + o));
            float z = gumbelf(bits) + lg[o];
            if (z > best) { best = z; bi = o; bl = lg[o]; }
          }
          action = bi; la = bl;
        } else {       // categorical over logits[:, 8:12], then +8
          float best = -3.0e38f; int bi = 0; float bl = lg[S0v];
#pragma unroll
          for (int o = 0; o < 4; ++o) {
            uint32_t bits = tf_bits32(k0, k1, (uint32_t)(b*4 + o));
            float z = gumbelf(bits) + lg[S0v + o];
            if (z > best) { best = z; bi = o; bl = lg[S0v + o]; }
          }
          action = S0v + bi; la = bl;
        }

        // log_softmax over FULL logits at chosen action
        float mx = lg[0];
#pragma unroll
        for (int o = 1; o < OUTv; ++o) mx = fmaxf(mx, lg[o]);
        float se = 0.f;
#pragma unroll
        for (int o = 0; o < OUTv; ++o) se += expf(lg[o] - mx);
        float lp = (la - mx) - logf(se);

        out[i*Bv + b]          = (float)action;  // output 0: actions (T,B)
        out[STEPS + i*Bv + b]  = lp;             // output 1: log-probs (T,B)
      }
    }
  }
}

extern "C" void kernel_launch(void* const* d_in, const int* in_sizes, int n_in,
                              void* d_out, int out_size, void* d_ws, size_t ws_size,
                              hipStream_t stream) {
  const float* Wih0 = (const float*)d_in[0];
  const float* Whh0 = (const float*)d_in[1];
  const float* b0   = (const float*)d_in[2];
  const float* Wih1 = (const float*)d_in[3];
  const float* Whh1 = (const float*)d_in[4];
  const float* b1   = (const float*)d_in[5];
  const float* gam  = (const float*)d_in[6];
  const float* bet  = (const float*)d_in[7];
  const float* Wout = (const float*)d_in[8];
  const float* bout = (const float*)d_in[9];
  const float* h0   = (const float*)d_in[10];
  const float* c0   = (const float*)d_in[11];

  net_persistent<<<dim3(NBLK), dim3(256), 0, stream>>>(
      Wih0, Whh0, b0, Wih1, Whh1, b1, gam, bet, Wout, bout, h0, c0,
      (float*)d_out, (uint32_t*)d_ws);
}

// Round 2
// 55958.063 us; speedup vs baseline: 1.7360x; 1.7360x over previous
//
#include <hip/hip_runtime.h>
#include <stdint.h>
#include <math.h>

// Problem constants
#define Bv      512
#define INv     64
#define Hv      512
#define OUTv    12
#define Tv      31
#define S0v     8
#define STEPS   (Tv*Bv)        // 15872 sequential LSTM steps per layer

// Workgroup roles
#define KA      32             // layer-0 WGs (16 h each, 4 h per wave)
#define KB      64             // layer-1 WGs (8 h each, 2 h per wave)
#define KPP     16             // postproc WGs
#define NBLK    (KA+KB+KPP)    // 112 blocks -> co-resident on 256 CUs
#define RING    8              // comm ring depth (power of 2)

// ws layout (bytes)
//  [0 , 256)    : l1prog  u32[64]   (layer-1 progress, relaxed)
//  [256, 512)   : iterflag u32[64]  (per-L1-WG completed-iteration count)
//  [4096, +32K) : h0comm  u64[RING][512]  (tag<<32 | float bits)
//  [36864,+32K) : y1comm  u64[RING][512]
//  [69632, ...) : ys1     float[STEPS][512]  (plain, fenced per iteration)

// ---------------- threefry2x32 (JAX-exact) ----------------
__device__ __forceinline__ uint32_t rotl32(uint32_t v, int r){ return (v<<r)|(v>>(32-r)); }

__device__ __forceinline__ void threefry2x32(uint32_t k0, uint32_t k1,
                                             uint32_t x0, uint32_t x1,
                                             uint32_t& o0, uint32_t& o1) {
  uint32_t ks2 = k0 ^ k1 ^ 0x1BD11BDAu;
  x0 += k0; x1 += k1;
#define TFR(r) { x0 += x1; x1 = rotl32(x1, r); x1 ^= x0; }
  TFR(13) TFR(15) TFR(26) TFR(6)
  x0 += k1;  x1 += ks2 + 1u;
  TFR(17) TFR(29) TFR(16) TFR(24)
  x0 += ks2; x1 += k0 + 2u;
  TFR(13) TFR(15) TFR(26) TFR(6)
  x0 += k0;  x1 += k1 + 3u;
  TFR(17) TFR(29) TFR(16) TFR(24)
  x0 += k1;  x1 += ks2 + 4u;
  TFR(13) TFR(15) TFR(26) TFR(6)
  x0 += ks2; x1 += k0 + 5u;
#undef TFR
  o0 = x0; o1 = x1;
}

__device__ __forceinline__ uint32_t tf_bits32(uint32_t k0, uint32_t k1, uint32_t j) {
  uint32_t a, b;
  threefry2x32(k0, k1, 0u, j, a, b);
  return a ^ b;
}

__device__ __forceinline__ float u32_to_uniform(uint32_t bits) {
  float f = __uint_as_float(0x3F800000u | (bits >> 9)) - 1.0f;
  const float TINY = 1.17549435e-38f;
  return fmaxf(TINY, f + TINY);
}

__device__ __forceinline__ float gumbelf(uint32_t bits) {
  float u = u32_to_uniform(bits);
  return -logf(-logf(u));
}

__device__ __forceinline__ float sigmf(float x) {
  if (x >= 0.f) { float z = expf(-x); return 1.f/(1.f+z); }
  float z = expf(x); return z/(1.f+z);
}

// Butterfly: halve per-lane row-partials across lanes (xor mask m).
template<int N>
__device__ __forceinline__ void bfly_halve(float* v, int m) {
  int lane = threadIdx.x & 63;
  bool up = (lane & m) != 0;
#pragma unroll
  for (int j = 0; j < N/2; ++j) {
    float send = up ? v[j] : v[j + N/2];
    float recv = __shfl_xor(send, m, 64);
    v[j] = (up ? v[j + N/2] : v[j]) + recv;
  }
}

__device__ __forceinline__ uint64_t aload64(const uint64_t* p){
  return __hip_atomic_load(p, __ATOMIC_RELAXED, __HIP_MEMORY_SCOPE_AGENT);
}
__device__ __forceinline__ void astore64(uint64_t* p, uint64_t v){
  __hip_atomic_store(p, v, __ATOMIC_RELAXED, __HIP_MEMORY_SCOPE_AGENT);
}
__device__ __forceinline__ uint32_t aload32(const uint32_t* p){
  return __hip_atomic_load(p, __ATOMIC_RELAXED, __HIP_MEMORY_SCOPE_AGENT);
}
__device__ __forceinline__ void astore32(uint32_t* p, uint32_t v){
  __hip_atomic_store(p, v, __ATOMIC_RELAXED, __HIP_MEMORY_SCOPE_AGENT);
}
__device__ __forceinline__ uint32_t tagof(uint64_t w){ return (uint32_t)(w>>32); }
__device__ __forceinline__ float    valof(uint64_t w){ return __uint_as_float((uint32_t)w); }
__device__ __forceinline__ uint64_t mkword(uint32_t t, float v){
  return ((uint64_t)t<<32) | (uint64_t)__float_as_uint(v);
}

__global__ __launch_bounds__(256, 1)
void net_persistent(const float* __restrict__ Wih0, const float* __restrict__ Whh0,
                    const float* __restrict__ b0,
                    const float* __restrict__ Wih1, const float* __restrict__ Whh1,
                    const float* __restrict__ b1,
                    const float* __restrict__ gamma, const float* __restrict__ beta,
                    const float* __restrict__ Wout, const float* __restrict__ bout,
                    const float* __restrict__ h0in, const float* __restrict__ c0in,
                    float* __restrict__ out, uint32_t* __restrict__ wsu)
{
  uint32_t* l1prog   = wsu;        // [64]
  uint32_t* iterflag = wsu + 64;   // [64]
  uint64_t* h0comm = (uint64_t*)((char*)wsu + 4096);
  uint64_t* y1comm = (uint64_t*)((char*)wsu + 4096 + RING*Hv*8);
  float*    ys1    = (float*)((char*)wsu + 4096 + 2*RING*Hv*8);

  const int bid  = blockIdx.x;
  const int tid  = threadIdx.x;
  const int wave = tid >> 6;
  const int lane = tid & 63;

  __shared__ float hbuf[2][Hv];      // L0 input double-buffer
  __shared__ float xbuf[2][2*Hv];    // L1 input double-buffer [x | hprev]
  __shared__ float Wout_s[OUTv*Hv];
  __shared__ float mu_s[Hv], isd_s[Hv], gam_s[Hv], bet_s[Hv];

  if (bid < KA) {
    // ================= Layer 0 =================
    const int hbase = bid*16;
    // rows r = jl*4 + g (jl = local h 0..3 within wave, g = gate).
    // lane's cols: {k*256 + lane*4 + c}, k=0..1, c=0..3  (conflict-free b128 LDS reads)
    float w[128];
#pragma unroll
    for (int jl = 0; jl < 4; ++jl)
#pragma unroll
      for (int g = 0; g < 4; ++g) {
        int r = jl*4 + g;
        const float* rp = Whh0 + (size_t)(g*Hv + hbase + wave*4 + jl)*Hv;
#pragma unroll
        for (int k = 0; k < 2; ++k) {
          float4 q = *(const float4*)(rp + k*256 + lane*4);
          w[r*8+k*4+0]=q.x; w[r*8+k*4+1]=q.y; w[r*8+k*4+2]=q.z; w[r*8+k*4+3]=q.w;
        }
      }
    // gate constants (x = ones folded) + c-state, publishing lanes 0..3
    float cgi=0.f, cgf=0.f, cgg=0.f, cgo=0.f, cst=0.f;
    const int hg = hbase + wave*4 + (lane & 3);
    if (lane < 4) {
      float s0=b0[0*Hv+hg], s1=b0[1*Hv+hg], s2=b0[2*Hv+hg], s3=b0[3*Hv+hg];
      for (int k = 0; k < INv; ++k) {
        s0 += Wih0[(size_t)(0*Hv+hg)*INv+k];
        s1 += Wih0[(size_t)(1*Hv+hg)*INv+k];
        s2 += Wih0[(size_t)(2*Hv+hg)*INv+k];
        s3 += Wih0[(size_t)(3*Hv+hg)*INv+k];
      }
      cgi=s0; cgf=s1; cgg=s2; cgo=s3;
      cst = c0in[hg];
    }

    for (int s = 0; s < STEPS; ++s) {
      const int par = s & 1;
      // throttle prefetch (overlapped with poll+compute)
      const bool chk = (s >= 6);
      uint32_t pv = 0u;
      if (chk) pv = aload32(l1prog + lane);
      // phase A: poll previous h into LDS
      {
        int idx = tid*2;
        if (s == 0) {
          hbuf[0][idx] = h0in[idx]; hbuf[0][idx+1] = h0in[idx+1];
        } else {
          uint64_t* src = h0comm + (size_t)((s-1)&(RING-1))*Hv + idx;
          uint32_t want = (uint32_t)s;
          uint64_t a = aload64(src), b2 = aload64(src+1);
          while (tagof(a) != want || tagof(b2) != want) {
            a = aload64(src); b2 = aload64(src+1);
          }
          hbuf[par][idx] = valof(a); hbuf[par][idx+1] = valof(b2);
        }
      }
      __syncthreads();
      // compute: 16 rows x 8 cols per lane
      const float4* hv = (const float4*)(hbuf[par]);
      float4 vA = hv[lane], vB = hv[64 + lane];
      float acc[16];
#pragma unroll
      for (int r = 0; r < 16; ++r) {
        float a = 0.f;
        a = fmaf(w[r*8+0], vA.x, a); a = fmaf(w[r*8+1], vA.y, a);
        a = fmaf(w[r*8+2], vA.z, a); a = fmaf(w[r*8+3], vA.w, a);
        a = fmaf(w[r*8+4], vB.x, a); a = fmaf(w[r*8+5], vB.y, a);
        a = fmaf(w[r*8+6], vB.z, a); a = fmaf(w[r*8+7], vB.w, a);
        acc[r] = a;
      }
      bfly_halve<16>(acc, 32);
      bfly_halve<8>(acc, 16);
      bfly_halve<4>(acc, 8);
      bfly_halve<2>(acc, 4);
      acc[0] += __shfl_xor(acc[0], 2, 64);
      acc[0] += __shfl_xor(acc[0], 1, 64);   // lane holds row (lane>>2)
      // gather the 4 gates of h (lane&3) from lanes 16*jl + 4*g
      int jl = lane & 3;
      float gi = __shfl(acc[0], 16*jl + 0,  64);
      float gf = __shfl(acc[0], 16*jl + 4,  64);
      float gg = __shfl(acc[0], 16*jl + 8,  64);
      float go = __shfl(acc[0], 16*jl + 12, 64);
      // throttle enforce: layer-1 must have consumed tag s-7 before we overwrite
      if (chk) {
        uint32_t need = (uint32_t)(s - 5);
        while (!__all((int)(pv >= need && pv <= (uint32_t)STEPS)))
          pv = aload32(l1prog + lane);
      }
      if (lane < 4) {
        float cc = sigmf(gf+cgf)*cst + sigmf(gi+cgi)*tanhf(gg+cgg);
        float hh = sigmf(go+cgo)*tanhf(cc);
        cst = cc;
        astore64(h0comm + (size_t)(s&(RING-1))*Hv + hg, mkword((uint32_t)(s+1), hh));
      }
    }
  } else if (bid < KA + KB) {
    // ================= Layer 1 =================
    const int wg1 = bid - KA;
    const int hbase = wg1*8;
    // rows r = jl*4 + g (jl 0..1). lane cols: {k*256 + lane*4 + c}, k=0..3.
    float w[128];
#pragma unroll
    for (int jl = 0; jl < 2; ++jl)
#pragma unroll
      for (int g = 0; g < 4; ++g) {
        int r = jl*4 + g;
        int row = g*Hv + hbase + wave*2 + jl;
#pragma unroll
        for (int k = 0; k < 4; ++k) {
          int col = k*256 + lane*4;
          const float* M = (col < Hv) ? (Wih1 + (size_t)row*Hv + col)
                                      : (Whh1 + (size_t)row*Hv + (col - Hv));
          float4 q = *(const float4*)M;
          w[r*16+k*4+0]=q.x; w[r*16+k*4+1]=q.y; w[r*16+k*4+2]=q.z; w[r*16+k*4+3]=q.w;
        }
      }
    float cgi=0.f, cgf=0.f, cgg=0.f, cgo=0.f, cst=0.f;
    const int hg = hbase + wave*2 + (lane & 1);
    if (lane < 2) {
      cgi = b1[0*Hv+hg]; cgf = b1[1*Hv+hg]; cgg = b1[2*Hv+hg]; cgo = b1[3*Hv+hg];
      cst = c0in[Hv + hg];
    }

    for (int s = 0; s < STEPS; ++s) {
      const int par = s & 1;
      // phase A: poll x = h0[s] (tag s+1) and hprev = ys1[s-1] (tag s)
      {
        int j0 = tid*4;
        if (j0 < Hv) {
          uint64_t* src = h0comm + (size_t)(s&(RING-1))*Hv + j0;
          uint32_t want = (uint32_t)(s+1);
          uint64_t a=aload64(src), b2=aload64(src+1), c2=aload64(src+2), d2=aload64(src+3);
          while (tagof(a)!=want || tagof(b2)!=want || tagof(c2)!=want || tagof(d2)!=want) {
            a=aload64(src); b2=aload64(src+1); c2=aload64(src+2); d2=aload64(src+3);
          }
          xbuf[par][j0]=valof(a); xbuf[par][j0+1]=valof(b2);
          xbuf[par][j0+2]=valof(c2); xbuf[par][j0+3]=valof(d2);
        } else {
          if (s == 0) {
            xbuf[0][j0]   = h0in[j0];     // h0in[512..1023] = layer-1 h0
            xbuf[0][j0+1] = h0in[j0+1];
            xbuf[0][j0+2] = h0in[j0+2];
            xbuf[0][j0+3] = h0in[j0+3];
          } else {
            uint64_t* src = y1comm + (size_t)((s-1)&(RING-1))*Hv + (j0 - Hv);
            uint32_t want = (uint32_t)s;
            uint64_t a=aload64(src), b2=aload64(src+1), c2=aload64(src+2), d2=aload64(src+3);
            while (tagof(a)!=want || tagof(b2)!=want || tagof(c2)!=want || tagof(d2)!=want) {
              a=aload64(src); b2=aload64(src+1); c2=aload64(src+2); d2=aload64(src+3);
            }
            xbuf[par][j0]=valof(a); xbuf[par][j0+1]=valof(b2);
            xbuf[par][j0+2]=valof(c2); xbuf[par][j0+3]=valof(d2);
          }
        }
      }
      __syncthreads();
      if (tid == 0) astore32(l1prog + wg1, (uint32_t)(s+1));  // consumed h0 tag s+1
      // compute: 8 rows x 16 cols per lane
      const float4* xv = (const float4*)(xbuf[par]);
      float4 v0 = xv[lane], v1 = xv[64+lane], v2 = xv[128+lane], v3 = xv[192+lane];
      float acc[8];
#pragma unroll
      for (int r = 0; r < 8; ++r) {
        float a = 0.f;
        a = fmaf(w[r*16+ 0], v0.x, a); a = fmaf(w[r*16+ 1], v0.y, a);
        a = fmaf(w[r*16+ 2], v0.z, a); a = fmaf(w[r*16+ 3], v0.w, a);
        a = fmaf(w[r*16+ 4], v1.x, a); a = fmaf(w[r*16+ 5], v1.y, a);
        a = fmaf(w[r*16+ 6], v1.z, a); a = fmaf(w[r*16+ 7], v1.w, a);
        a = fmaf(w[r*16+ 8], v2.x, a); a = fmaf(w[r*16+ 9], v2.y, a);
        a = fmaf(w[r*16+10], v2.z, a); a = fmaf(w[r*16+11], v2.w, a);
        a = fmaf(w[r*16+12], v3.x, a); a = fmaf(w[r*16+13], v3.y, a);
        a = fmaf(w[r*16+14], v3.z, a); a = fmaf(w[r*16+15], v3.w, a);
        acc[r] = a;
      }
      bfly_halve<8>(acc, 32);
      bfly_halve<4>(acc, 16);
      bfly_halve<2>(acc, 8);
      acc[0] += __shfl_xor(acc[0], 4, 64);
      acc[0] += __shfl_xor(acc[0], 2, 64);
      acc[0] += __shfl_xor(acc[0], 1, 64);   // lane holds row (lane>>3)
      int jl = lane & 1;
      float gi = __shfl(acc[0], 32*jl + 0,  64);
      float gf = __shfl(acc[0], 32*jl + 8,  64);
      float gg = __shfl(acc[0], 32*jl + 16, 64);
      float go = __shfl(acc[0], 32*jl + 24, 64);
      if (lane < 2) {
        float cc = sigmf(gf+cgf)*cst + sigmf(gi+cgi)*tanhf(gg+cgg);
        float hh = sigmf(go+cgo)*tanhf(cc);
        cst = cc;
        astore64(y1comm + (size_t)(s&(RING-1))*Hv + hg, mkword((uint32_t)(s+1), hh));
        ys1[(size_t)s*Hv + hg] = hh;   // plain store for postproc
      }
      if ((s & 511) == 511) {
        __syncthreads();   // drain all waves' ys1 stores (barrier waits vmcnt)
        if (tid == 0) {
          __builtin_amdgcn_fence(__ATOMIC_RELEASE, "agent");  // L2 writeback
          astore32(iterflag + wg1, (uint32_t)((s >> 9) + 1));
        }
      }
    }
  } else {
    // ================= Postprocess =================
    const int p = bid - KA - KB;
    for (int r = tid; r < OUTv*Hv; r += 256) Wout_s[r] = Wout[r];
    for (int h = tid; h < Hv; h += 256) { gam_s[h] = gamma[h]; bet_s[h] = beta[h]; }
    float bo[OUTv];
#pragma unroll
    for (int o = 0; o < OUTv; ++o) bo[o] = bout[o];
    __syncthreads();

    for (int i = p; i < Tv; i += KPP) {
      const uint32_t tgt = (uint32_t)(i + 1);
      if (tid < 64) {
        for (;;) {
          uint32_t v = aload32(iterflag + lane);
          if (__all((int)(v >= tgt && v <= (uint32_t)Tv))) break;
        }
      }
      __syncthreads();
      __builtin_amdgcn_fence(__ATOMIC_ACQUIRE, "agent");

      const float* Y = ys1 + (size_t)i * Bv * Hv;

      for (int h = tid; h < Hv; h += 256) {
        double sum = 0.0, sq = 0.0;
        for (int b = 0; b < Bv; ++b) {
          double v = (double)Y[(size_t)b*Hv + h];
          sum += v; sq += v*v;
        }
        double mu = sum * (1.0/512.0);
        double var = sq * (1.0/512.0) - mu*mu;
        if (var < 0.0) var = 0.0;
        mu_s[h]  = (float)mu;
        isd_s[h] = (float)(1.0 / sqrt(var + 1e-5));
      }
      __syncthreads();

      uint32_t k0, k1;
      threefry2x32(0u, 42u, 0u, (uint32_t)i, k0, k1);

      for (int b = tid; b < Bv; b += 256) {
        float lg[OUTv];
#pragma unroll
        for (int o = 0; o < OUTv; ++o) lg[o] = 0.f;
        const float* Yb = Y + (size_t)b * Hv;
        for (int h = 0; h < Hv; ++h) {
          float yn = (Yb[h] - mu_s[h]) * isd_s[h] * gam_s[h] + bet_s[h];
          float gv = expf(-yn*yn);
#pragma unroll
          for (int o = 0; o < OUTv; ++o) lg[o] = fmaf(gv, Wout_s[o*Hv + h], lg[o]);
        }
#pragma unroll
        for (int o = 0; o < OUTv; ++o) lg[o] += bo[o];

        int action; float la;
        if (i < 15) {
          float best = -3.0e38f; int bi = 0; float bl = lg[0];
#pragma unroll
          for (int o = 0; o < OUTv; ++o) {
            uint32_t bits = tf_bits32(k0, k1, (uint32_t)(b*12 + o));
            float z = gumbelf(bits) + lg[o];
            if (z > best) { best = z; bi = o; bl = lg[o]; }
          }
          action = bi; la = bl;
        } else {
          float best = -3.0e38f; int bi = 0; float bl = lg[S0v];
#pragma unroll
          for (int o = 0; o < 4; ++o) {
            uint32_t bits = tf_bits32(k0, k1, (uint32_t)(b*4 + o));
            float z = gumbelf(bits) + lg[S0v + o];
            if (z > best) { best = z; bi = o; bl = lg[S0v + o]; }
          }
          action = S0v + bi; la = bl;
        }

        float mx = lg[0];
#pragma unroll
        for (int o = 1; o < OUTv; ++o) mx = fmaxf(mx, lg[o]);
        float se = 0.f;
#pragma unroll
        for (int o = 0; o < OUTv; ++o) se += expf(lg[o] - mx);
        float lp = (la - mx) - logf(se);

        out[i*Bv + b]         = (float)action;
        out[STEPS + i*Bv + b] = lp;
      }
    }
  }
}

extern "C" void kernel_launch(void* const* d_in, const int* in_sizes, int n_in,
                              void* d_out, int out_size, void* d_ws, size_t ws_size,
                              hipStream_t stream) {
  const float* Wih0 = (const float*)d_in[0];
  const float* Whh0 = (const float*)d_in[1];
  const float* b0   = (const float*)d_in[2];
  const float* Wih1 = (const float*)d_in[3];
  const float* Whh1 = (const float*)d_in[4];
  const float* b1   = (const float*)d_in[5];
  const float* gam  = (const float*)d_in[6];
  const float* bet  = (const float*)d_in[7];
  const float* Wout = (const float*)d_in[8];
  const float* bout = (const float*)d_in[9];
  const float* h0   = (const float*)d_in[10];
  const float* c0   = (const float*)d_in[11];

  net_persistent<<<dim3(NBLK), dim3(256), 0, stream>>>(
      Wih0, Whh0, b0, Wih1, Whh1, b1, gam, bet, Wout, bout, h0, c0,
      (float*)d_out, (uint32_t*)d_ws);
}